// Round 14
// baseline (249.190 us; speedup 1.0000x reference)
//
#include <hip/hip_runtime.h>

#define N_SRC 50000
#define N_DST1 20000
#define N_DST2 10000
#define E1 320000
#define E2 160000
#define T 12
#define C_IN 64
#define HID 16
#define C_OUT 32

__device__ __forceinline__ float lrelu(float x, float s) { return x > 0.f ? x : s * x; }

// Bijective XCD-aware swizzle: XCD x = p%8 owns a contiguous logical chunk.
__device__ __forceinline__ int xcd_swizzle(int p, int W) {
    int x = p & 7, k = p >> 3;
    int q = W >> 3, r = W & 7;
    return (x < r ? x * (q + 1) : r * (q + 1) + (x - r) * q) + k;
}

// ---------------- Layer-1 transform: 64-node tile, ~21.6KB LDS ----------
// One node-quarter per thread; loads and hs1 stores exactly lane-contiguous.
__global__ __launch_bounds__(256) void k_transform1(
    const float* __restrict__ nf, const float* __restrict__ W1,
    const float* __restrict__ a_l, const float* __restrict__ a_r,
    float* __restrict__ hs1, float* __restrict__ el1, float* __restrict__ er1)
{
    __shared__ float xs[64][68];
    __shared__ float w[C_IN][HID];
    __shared__ float al[HID], ar[HID];
    int tx = threadIdx.x;
    int t = blockIdx.y;
    int n0 = blockIdx.x * 64;
    int nrem = N_SRC - n0; if (nrem > 64) nrem = 64;

    reinterpret_cast<float4*>(&w[0][0])[tx] = reinterpret_cast<const float4*>(W1)[tx];
    if (tx < HID) al[tx] = a_l[tx];
    else if (tx < 2 * HID) ar[tx - HID] = a_r[tx - HID];

    const float4* gp = reinterpret_cast<const float4*>(nf + ((size_t)t * N_SRC + n0) * C_IN);
#pragma unroll
    for (int k = 0; k < 4; k++) {
        int f = k * 256 + tx;
        int node = f >> 4;
        if (node < nrem)
            *reinterpret_cast<float4*>(&xs[node][(f & 15) * 4]) = gp[f];
    }
    __syncthreads();

    int q = tx & 3;
    int nn = tx >> 2;              // 0..63: this thread's node
    float4 acc = make_float4(0.f, 0.f, 0.f, 0.f);
#pragma unroll
    for (int c4 = 0; c4 < 16; c4++) {
        float4 xA = *reinterpret_cast<const float4*>(&xs[nn][c4 * 4]);
        float4 w0 = *reinterpret_cast<const float4*>(&w[c4 * 4 + 0][q * 4]);
        float4 w1 = *reinterpret_cast<const float4*>(&w[c4 * 4 + 1][q * 4]);
        float4 w2 = *reinterpret_cast<const float4*>(&w[c4 * 4 + 2][q * 4]);
        float4 w3 = *reinterpret_cast<const float4*>(&w[c4 * 4 + 3][q * 4]);
        acc.x += xA.x * w0.x + xA.y * w1.x + xA.z * w2.x + xA.w * w3.x;
        acc.y += xA.x * w0.y + xA.y * w1.y + xA.z * w2.y + xA.w * w3.y;
        acc.z += xA.x * w0.z + xA.y * w1.z + xA.z * w2.z + xA.w * w3.z;
        acc.w += xA.x * w0.w + xA.y * w1.w + xA.z * w2.w + xA.w * w3.w;
    }

    float el = acc.x * al[q * 4] + acc.y * al[q * 4 + 1] + acc.z * al[q * 4 + 2] + acc.w * al[q * 4 + 3];
    float er = acc.x * ar[q * 4] + acc.y * ar[q * 4 + 1] + acc.z * ar[q * 4 + 2] + acc.w * ar[q * 4 + 3];
    el += __shfl_xor(el, 1); el += __shfl_xor(el, 2);
    er += __shfl_xor(er, 1); er += __shfl_xor(er, 2);

    if (nn < nrem) {
        float* hb = hs1 + ((size_t)t * N_SRC + n0) * HID;
        *reinterpret_cast<float4*>(hb + (size_t)nn * HID + q * 4) = acc;
        if (q == 0) {
            int n = n0 + nn;
            el1[(size_t)t * N_SRC + n] = el;
            if (n < N_DST1) er1[(size_t)t * N_DST1 + n] = er;
        }
    }
}

// ---------------- fused CSR: LDS histogram + scan + wvec (3 blocks) -----
__global__ __launch_bounds__(1024) void k_csr(
    const int* __restrict__ d1, const int* __restrict__ d2,
    int* __restrict__ off1, int* __restrict__ cur1,
    int* __restrict__ off2, int* __restrict__ cur2,
    const float* __restrict__ W2, const float* __restrict__ al2,
    const float* __restrict__ ar2, float* __restrict__ wl2, float* __restrict__ wr2)
{
    __shared__ int cnt[N_DST1];    // 80KB; max of the two layer sizes
    __shared__ int part[1024];
    int tx = threadIdx.x;
    if (blockIdx.x == 2) {
        if (tx < 32) {
            int c = tx & 15;
            const float* a = (tx < 16) ? al2 : ar2;
            float s = 0.f;
            for (int o = 0; o < C_OUT; o++) s += W2[c * C_OUT + o] * a[o];
            if (tx < 16) wl2[c] = s; else wr2[c] = s;
        }
        return;
    }
    const int* dst = (blockIdx.x == 0) ? d1 : d2;
    int E = (blockIdx.x == 0) ? E1 : E2;
    int N = (blockIdx.x == 0) ? N_DST1 : N_DST2;
    int* off = (blockIdx.x == 0) ? off1 : off2;
    int* cur = (blockIdx.x == 0) ? cur1 : cur2;

    for (int i = tx; i < N; i += 1024) cnt[i] = 0;
    __syncthreads();
    for (int e = tx; e < E; e += 1024) atomicAdd(&cnt[dst[e]], 1);
    __syncthreads();

    int CH = (N + 1023) / 1024;
    int base = tx * CH;
    int p = 0;
    for (int k = 0; k < CH; k++) { int i = base + k; if (i < N) p += cnt[i]; }
    part[tx] = p;
    __syncthreads();
#pragma unroll
    for (int dd = 1; dd < 1024; dd <<= 1) {
        int v = (tx >= dd) ? part[tx - dd] : 0;
        __syncthreads();
        part[tx] += v;
        __syncthreads();
    }
    int run = (tx == 0) ? 0 : part[tx - 1];
    if (tx == 0) off[0] = 0;
    for (int k = 0; k < CH; k++) {
        int i = base + k;
        if (i < N) { cur[i] = run; run += cnt[i]; off[i + 1] = run; }
    }
}

__global__ __launch_bounds__(256) void k_scatter(
    const int* __restrict__ s1, const int* __restrict__ d1, const float* __restrict__ w1,
    int* __restrict__ cur1, int2* __restrict__ sw1,
    const int* __restrict__ s2, const int* __restrict__ d2, const float* __restrict__ w2,
    int* __restrict__ cur2, int2* __restrict__ sw2)
{
    int e = blockIdx.x * 256 + threadIdx.x;
    if (e < E1) {
        int d = d1[e];
        int p = atomicAdd(&cur1[d], 1);
        sw1[p] = make_int2(s1[e], __float_as_int(w1[e]));
    } else if (e < E1 + E2) {
        int ee = e - E1;
        int d = d2[ee];
        int p = atomicAdd(&cur2[d], 1);
        sw2[p] = make_int2(s2[ee], __float_as_int(w2[ee]));
    }
}

// ---------------- fused GAT layer: 16 lanes per (dst,t) -----------------
// lane16 = eslot*4 + q. Inner loop unrolled x2, independent gather chains.
// No max shift: logits bounded (|lg| <~ 4 for this model), den >= ~6.
template <int NDST, int NSRC, bool FINAL>
__global__ __launch_bounds__(256) void k_gat(
    const int* __restrict__ off, const int2* __restrict__ sw,
    const float* __restrict__ el, const float* __restrict__ er,
    const float* __restrict__ hs, float* __restrict__ outp,
    const float* __restrict__ wl, const float* __restrict__ wr,
    float* __restrict__ el_out, float* __restrict__ er_out)
{
    __shared__ float w2s[FINAL ? HID * C_OUT : 1];
    int tx = threadIdx.x;
    if (FINAL) {
        for (int idx = tx; idx < HID * C_OUT; idx += 256) w2s[idx] = wl[idx];
        __syncthreads();
    }
    int wblk = xcd_swizzle(blockIdx.x, (NDST * T) / 16);
    int grp = tx >> 4;
    int lane16 = tx & 15;
    int q = lane16 & 3;
    int eslot = lane16 >> 2;
    int g = wblk * 16 + grp;       // t*NDST + d
    int t = g / NDST;
    int d = g - t * NDST;
    int start = off[d], end = off[d + 1];
    float erv = er[g];
    const float* elb = el + (size_t)t * NSRC;
    const float* hsb = hs + (size_t)t * NSRC * HID;

    float4 num = make_float4(0.f, 0.f, 0.f, 0.f);
    float den = 0.f;
    int i = start + eslot;
    for (; i + 4 < end; i += 8) {
        int2 sa = sw[i];
        int2 sb = sw[i + 4];
        float ea = elb[sa.x];
        float eb = elb[sb.x];
        float4 ha = *reinterpret_cast<const float4*>(hsb + (size_t)sa.x * HID + q * 4);
        float4 hb = *reinterpret_cast<const float4*>(hsb + (size_t)sb.x * HID + q * 4);
        float exa = __expf(lrelu(ea + erv, 0.2f));
        float exb = __expf(lrelu(eb + erv, 0.2f));
        den += exa + exb;
        float ca = exa * __int_as_float(sa.y);
        float cb = exb * __int_as_float(sb.y);
        num.x += ca * ha.x + cb * hb.x;
        num.y += ca * ha.y + cb * hb.y;
        num.z += ca * ha.z + cb * hb.z;
        num.w += ca * ha.w + cb * hb.w;
    }
    if (i < end) {
        int2 sa = sw[i];
        float ea = elb[sa.x];
        float4 ha = *reinterpret_cast<const float4*>(hsb + (size_t)sa.x * HID + q * 4);
        float exa = __expf(lrelu(ea + erv, 0.2f));
        den += exa;
        float ca = exa * __int_as_float(sa.y);
        num.x += ca * ha.x; num.y += ca * ha.y;
        num.z += ca * ha.z; num.w += ca * ha.w;
    }
    // reduce over eslot (lane bits 2..3)
#pragma unroll
    for (int mk = 4; mk <= 8; mk <<= 1) {
        num.x += __shfl_xor(num.x, mk);
        num.y += __shfl_xor(num.y, mk);
        num.z += __shfl_xor(num.z, mk);
        num.w += __shfl_xor(num.w, mk);
        den   += __shfl_xor(den, mk);
    }
    float inv = 1.f / (den + 1e-9f);
    float4 v = make_float4(num.x * inv, num.y * inv, num.z * inv, num.w * inv);

    if (!FINAL) {
        v.x = lrelu(v.x, 0.01f); v.y = lrelu(v.y, 0.01f);
        v.z = lrelu(v.z, 0.01f); v.w = lrelu(v.w, 0.01f);
        if (eslot == 0) {
            *reinterpret_cast<float4*>(outp + (size_t)g * HID + q * 4) = v;
            float pl = v.x * wl[q * 4] + v.y * wl[q * 4 + 1] + v.z * wl[q * 4 + 2] + v.w * wl[q * 4 + 3];
            float pr = v.x * wr[q * 4] + v.y * wr[q * 4 + 1] + v.z * wr[q * 4 + 2] + v.w * wr[q * 4 + 3];
            pl += __shfl_xor(pl, 1); pl += __shfl_xor(pl, 2);
            pr += __shfl_xor(pr, 1); pr += __shfl_xor(pr, 2);
            if (q == 0) {
                el_out[g] = pl;
                if (d < N_DST2) er_out[(size_t)t * N_DST2 + d] = pr;
            }
        }
    } else {
        float4 v1, v2, v3;
        v1.x = __shfl_xor(v.x, 1); v1.y = __shfl_xor(v.y, 1); v1.z = __shfl_xor(v.z, 1); v1.w = __shfl_xor(v.w, 1);
        v2.x = __shfl_xor(v.x, 2); v2.y = __shfl_xor(v.y, 2); v2.z = __shfl_xor(v.z, 2); v2.w = __shfl_xor(v.w, 2);
        v3.x = __shfl_xor(v.x, 3); v3.y = __shfl_xor(v.y, 3); v3.z = __shfl_xor(v.z, 3); v3.w = __shfl_xor(v.w, 3);
        int obase = q * 8;
        float out8[8];
#pragma unroll
        for (int oo = 0; oo < 8; oo++) out8[oo] = 0.f;
#define ACCQ(Q, R0)                                                             \
        {                                                                       \
            int r0 = (R0) * 4;                                                  \
            _Pragma("unroll")                                                   \
            for (int oo = 0; oo < 8; oo++)                                      \
                out8[oo] += (Q).x * w2s[(r0 + 0) * C_OUT + obase + oo]          \
                          + (Q).y * w2s[(r0 + 1) * C_OUT + obase + oo]          \
                          + (Q).z * w2s[(r0 + 2) * C_OUT + obase + oo]          \
                          + (Q).w * w2s[(r0 + 3) * C_OUT + obase + oo];         \
        }
        ACCQ(v,  q);
        ACCQ(v1, q ^ 1);
        ACCQ(v2, q ^ 2);
        ACCQ(v3, q ^ 3);
#undef ACCQ
        if (eslot == 0) {
            float* op = outp + (size_t)g * C_OUT + obase;
            float4 w0 = make_float4(lrelu(out8[0], 0.01f), lrelu(out8[1], 0.01f),
                                    lrelu(out8[2], 0.01f), lrelu(out8[3], 0.01f));
            float4 w1 = make_float4(lrelu(out8[4], 0.01f), lrelu(out8[5], 0.01f),
                                    lrelu(out8[6], 0.01f), lrelu(out8[7], 0.01f));
            *reinterpret_cast<float4*>(op) = w0;
            *reinterpret_cast<float4*>(op + 4) = w1;
        }
    }
}

extern "C" void kernel_launch(void* const* d_in, const int* in_sizes, int n_in,
                              void* d_out, int out_size, void* d_ws, size_t ws_size,
                              hipStream_t stream)
{
    const float* node_feat = (const float*)d_in[0];
    const int*   esrc1     = (const int*)d_in[1];
    const int*   edst1     = (const int*)d_in[2];
    const float* ew1       = (const float*)d_in[3];
    const int*   esrc2     = (const int*)d_in[4];
    const int*   edst2     = (const int*)d_in[5];
    const float* ew2       = (const float*)d_in[6];
    const float* W1        = (const float*)d_in[7];
    const float* a_l1      = (const float*)d_in[8];
    const float* a_r1      = (const float*)d_in[9];
    const float* W2        = (const float*)d_in[10];
    const float* a_l2      = (const float*)d_in[11];
    const float* a_r2      = (const float*)d_in[12];
    float* out = (float*)d_out;

    float* ws = (float*)d_ws;
    float* hs1 = ws;                        // 9,600,000  [T][N_SRC][16]
    float* el1 = hs1 + 9600000;             //   600,000  [T][N_SRC]
    float* er1 = el1 + 600000;              //   240,000  [T][N_DST1]
    float* h1  = er1 + 240000;              // 3,840,000  [T][N_DST1][16]
    float* el2 = h1 + 3840000;              //   240,000  [T][N_DST1]
    float* er2 = el2 + 240000;              //   120,000  [T][N_DST2]
    float* wl2 = er2 + 120000;              //        16
    float* wr2 = wl2 + 16;                  //        16
    int2* sw1 = (int2*)(wr2 + 16);          // E1 (16B-aligned)
    int2* sw2 = sw1 + E1;                   // E2
    int* off1 = (int*)(sw2 + E2);           //  20,001
    int* cur1 = off1 + N_DST1 + 1;          //  20,000
    int* off2 = cur1 + N_DST1;              //  10,001
    int* cur2 = off2 + N_DST2 + 1;          //  10,000
    // total ~= 63 MB

    k_csr<<<3, 1024, 0, stream>>>(edst1, edst2, off1, cur1, off2, cur2,
                                  W2, a_l2, a_r2, wl2, wr2);
    k_scatter<<<(E1 + E2 + 255) / 256, 256, 0, stream>>>(
        esrc1, edst1, ew1, cur1, sw1,
        esrc2, edst2, ew2, cur2, sw2);

    {
        dim3 g((N_SRC + 63) / 64, T);
        k_transform1<<<g, 256, 0, stream>>>(node_feat, W1, a_l1, a_r1, hs1, el1, er1);
    }
    k_gat<N_DST1, N_SRC, false><<<(N_DST1 * T) / 16, 256, 0, stream>>>(
        off1, sw1, el1, er1, hs1, h1, wl2, wr2, el2, er2);
    k_gat<N_DST2, N_DST1, true><<<(N_DST2 * T) / 16, 256, 0, stream>>>(
        off2, sw2, el2, er2, h1, out, W2, nullptr, nullptr, nullptr);
}

// Round 15
// 209.212 us; speedup vs baseline: 1.1911x; 1.1911x over previous
//
#include <hip/hip_runtime.h>

#define N_SRC 50000
#define N_DST1 20000
#define N_DST2 10000
#define E1 320000
#define E2 160000
#define T 12
#define C_IN 64
#define HID 16
#define C_OUT 32

__device__ __forceinline__ float lrelu(float x, float s) { return x > 0.f ? x : s * x; }

// Bijective XCD-aware swizzle: XCD x = p%8 owns a contiguous logical chunk.
__device__ __forceinline__ int xcd_swizzle(int p, int W) {
    int x = p & 7, k = p >> 3;
    int q = W >> 3, r = W & 7;
    return (x < r ? x * (q + 1) : r * (q + 1) + (x - r) * q) + k;
}

__global__ __launch_bounds__(256) void k_zero(int4* __restrict__ p, int n4)
{
    int i = blockIdx.x * 256 + threadIdx.x;
    if (i < n4) p[i] = make_int4(0, 0, 0, 0);
}

// ---------------- Layer-1 transform: 64-node tile, ~21.6KB LDS ----------
__global__ __launch_bounds__(256) void k_transform1(
    const float* __restrict__ nf, const float* __restrict__ W1,
    const float* __restrict__ a_l, const float* __restrict__ a_r,
    float* __restrict__ hs1, float* __restrict__ el1, float* __restrict__ er1)
{
    __shared__ float xs[64][68];
    __shared__ float w[C_IN][HID];
    __shared__ float al[HID], ar[HID];
    int tx = threadIdx.x;
    int t = blockIdx.y;
    int n0 = blockIdx.x * 64;
    int nrem = N_SRC - n0; if (nrem > 64) nrem = 64;

    reinterpret_cast<float4*>(&w[0][0])[tx] = reinterpret_cast<const float4*>(W1)[tx];
    if (tx < HID) al[tx] = a_l[tx];
    else if (tx < 2 * HID) ar[tx - HID] = a_r[tx - HID];

    const float4* gp = reinterpret_cast<const float4*>(nf + ((size_t)t * N_SRC + n0) * C_IN);
#pragma unroll
    for (int k = 0; k < 4; k++) {
        int f = k * 256 + tx;
        int node = f >> 4;
        if (node < nrem)
            *reinterpret_cast<float4*>(&xs[node][(f & 15) * 4]) = gp[f];
    }
    __syncthreads();

    int q = tx & 3;
    int nn = tx >> 2;
    float4 acc = make_float4(0.f, 0.f, 0.f, 0.f);
#pragma unroll
    for (int c4 = 0; c4 < 16; c4++) {
        float4 xA = *reinterpret_cast<const float4*>(&xs[nn][c4 * 4]);
        float4 w0 = *reinterpret_cast<const float4*>(&w[c4 * 4 + 0][q * 4]);
        float4 w1 = *reinterpret_cast<const float4*>(&w[c4 * 4 + 1][q * 4]);
        float4 w2 = *reinterpret_cast<const float4*>(&w[c4 * 4 + 2][q * 4]);
        float4 w3 = *reinterpret_cast<const float4*>(&w[c4 * 4 + 3][q * 4]);
        acc.x += xA.x * w0.x + xA.y * w1.x + xA.z * w2.x + xA.w * w3.x;
        acc.y += xA.x * w0.y + xA.y * w1.y + xA.z * w2.y + xA.w * w3.y;
        acc.z += xA.x * w0.z + xA.y * w1.z + xA.z * w2.z + xA.w * w3.z;
        acc.w += xA.x * w0.w + xA.y * w1.w + xA.z * w2.w + xA.w * w3.w;
    }

    float el = acc.x * al[q * 4] + acc.y * al[q * 4 + 1] + acc.z * al[q * 4 + 2] + acc.w * al[q * 4 + 3];
    float er = acc.x * ar[q * 4] + acc.y * ar[q * 4 + 1] + acc.z * ar[q * 4 + 2] + acc.w * ar[q * 4 + 3];
    el += __shfl_xor(el, 1); el += __shfl_xor(el, 2);
    er += __shfl_xor(er, 1); er += __shfl_xor(er, 2);

    if (nn < nrem) {
        float* hb = hs1 + ((size_t)t * N_SRC + n0) * HID;
        *reinterpret_cast<float4*>(hb + (size_t)nn * HID + q * 4) = acc;
        if (q == 0) {
            int n = n0 + nn;
            el1[(size_t)t * N_SRC + n] = el;
            if (n < N_DST1) er1[(size_t)t * N_DST1 + n] = er;
        }
    }
}

// ---------------- CSR build: parallel hist + scan (+wvec) ---------------
__global__ __launch_bounds__(256) void k_hist(
    const int* __restrict__ d1, const int* __restrict__ d2,
    int* __restrict__ cnt1, int* __restrict__ cnt2)
{
    int e = blockIdx.x * 256 + threadIdx.x;
    if (e < E1) atomicAdd(&cnt1[d1[e]], 1);
    else if (e < E1 + E2) atomicAdd(&cnt2[d2[e - E1]], 1);
}

__device__ void scan_one(const int* cnt, int* off, int* cur, int N)
{
    __shared__ int part[1024];
    int tx = threadIdx.x;
    int CH = (N + 1023) / 1024;
    int base = tx * CH;
    int p = 0;
    for (int k = 0; k < CH; k++) { int i = base + k; if (i < N) p += cnt[i]; }
    part[tx] = p;
    __syncthreads();
#pragma unroll
    for (int d = 1; d < 1024; d <<= 1) {
        int v = (tx >= d) ? part[tx - d] : 0;
        __syncthreads();
        part[tx] += v;
        __syncthreads();
    }
    int run = (tx == 0) ? 0 : part[tx - 1];
    if (tx == 0) off[0] = 0;
    for (int k = 0; k < CH; k++) {
        int i = base + k;
        if (i < N) { cur[i] = run; run += cnt[i]; off[i + 1] = run; }
    }
}

__global__ __launch_bounds__(1024) void k_scan(
    const int* __restrict__ cnt1, int* __restrict__ off1, int* __restrict__ cur1,
    const int* __restrict__ cnt2, int* __restrict__ off2, int* __restrict__ cur2,
    const float* __restrict__ W2, const float* __restrict__ al2,
    const float* __restrict__ ar2, float* __restrict__ wl2, float* __restrict__ wr2)
{
    if (blockIdx.x == 2) {
        int tx = threadIdx.x;
        if (tx < 32) {
            int c = tx & 15;
            const float* a = (tx < 16) ? al2 : ar2;
            float s = 0.f;
            for (int o = 0; o < C_OUT; o++) s += W2[c * C_OUT + o] * a[o];
            if (tx < 16) wl2[c] = s; else wr2[c] = s;
        }
        return;
    }
    if (blockIdx.x == 0) scan_one(cnt1, off1, cur1, N_DST1);
    else                 scan_one(cnt2, off2, cur2, N_DST2);
}

__global__ __launch_bounds__(256) void k_scatter(
    const int* __restrict__ s1, const int* __restrict__ d1, const float* __restrict__ w1,
    int* __restrict__ cur1, int2* __restrict__ sw1,
    const int* __restrict__ s2, const int* __restrict__ d2, const float* __restrict__ w2,
    int* __restrict__ cur2, int2* __restrict__ sw2)
{
    int e = blockIdx.x * 256 + threadIdx.x;
    if (e < E1) {
        int d = d1[e];
        int p = atomicAdd(&cur1[d], 1);
        sw1[p] = make_int2(s1[e], __float_as_int(w1[e]));
    } else if (e < E1 + E2) {
        int ee = e - E1;
        int d = d2[ee];
        int p = atomicAdd(&cur2[d], 1);
        sw2[p] = make_int2(s2[ee], __float_as_int(w2[ee]));
    }
}

// ---------------- fused GAT layer: 16 lanes per (dst,t) -----------------
// lane16 = eslot*4 + q. Inner loop unrolled x2, independent gather chains.
// No max shift: logits bounded (|lg| <~ 4 for this model), den >= ~6.
template <int NDST, int NSRC, bool FINAL>
__global__ __launch_bounds__(256) void k_gat(
    const int* __restrict__ off, const int2* __restrict__ sw,
    const float* __restrict__ el, const float* __restrict__ er,
    const float* __restrict__ hs, float* __restrict__ outp,
    const float* __restrict__ wl, const float* __restrict__ wr,
    float* __restrict__ el_out, float* __restrict__ er_out)
{
    __shared__ float w2s[FINAL ? HID * C_OUT : 1];
    int tx = threadIdx.x;
    if (FINAL) {
        for (int idx = tx; idx < HID * C_OUT; idx += 256) w2s[idx] = wl[idx];
        __syncthreads();
    }
    int wblk = xcd_swizzle(blockIdx.x, (NDST * T) / 16);
    int grp = tx >> 4;
    int lane16 = tx & 15;
    int q = lane16 & 3;
    int eslot = lane16 >> 2;
    int g = wblk * 16 + grp;       // t*NDST + d
    int t = g / NDST;
    int d = g - t * NDST;
    int start = off[d], end = off[d + 1];
    float erv = er[g];
    const float* elb = el + (size_t)t * NSRC;
    const float* hsb = hs + (size_t)t * NSRC * HID;

    float4 num = make_float4(0.f, 0.f, 0.f, 0.f);
    float den = 0.f;
    int i = start + eslot;
    for (; i + 4 < end; i += 8) {
        int2 sa = sw[i];
        int2 sb = sw[i + 4];
        float ea = elb[sa.x];
        float eb = elb[sb.x];
        float4 ha = *reinterpret_cast<const float4*>(hsb + (size_t)sa.x * HID + q * 4);
        float4 hb = *reinterpret_cast<const float4*>(hsb + (size_t)sb.x * HID + q * 4);
        float exa = __expf(lrelu(ea + erv, 0.2f));
        float exb = __expf(lrelu(eb + erv, 0.2f));
        den += exa + exb;
        float ca = exa * __int_as_float(sa.y);
        float cb = exb * __int_as_float(sb.y);
        num.x += ca * ha.x + cb * hb.x;
        num.y += ca * ha.y + cb * hb.y;
        num.z += ca * ha.z + cb * hb.z;
        num.w += ca * ha.w + cb * hb.w;
    }
    if (i < end) {
        int2 sa = sw[i];
        float ea = elb[sa.x];
        float4 ha = *reinterpret_cast<const float4*>(hsb + (size_t)sa.x * HID + q * 4);
        float exa = __expf(lrelu(ea + erv, 0.2f));
        den += exa;
        float ca = exa * __int_as_float(sa.y);
        num.x += ca * ha.x; num.y += ca * ha.y;
        num.z += ca * ha.z; num.w += ca * ha.w;
    }
#pragma unroll
    for (int mk = 4; mk <= 8; mk <<= 1) {
        num.x += __shfl_xor(num.x, mk);
        num.y += __shfl_xor(num.y, mk);
        num.z += __shfl_xor(num.z, mk);
        num.w += __shfl_xor(num.w, mk);
        den   += __shfl_xor(den, mk);
    }
    float inv = 1.f / (den + 1e-9f);
    float4 v = make_float4(num.x * inv, num.y * inv, num.z * inv, num.w * inv);

    if (!FINAL) {
        v.x = lrelu(v.x, 0.01f); v.y = lrelu(v.y, 0.01f);
        v.z = lrelu(v.z, 0.01f); v.w = lrelu(v.w, 0.01f);
        if (eslot == 0) {
            *reinterpret_cast<float4*>(outp + (size_t)g * HID + q * 4) = v;
            float pl = v.x * wl[q * 4] + v.y * wl[q * 4 + 1] + v.z * wl[q * 4 + 2] + v.w * wl[q * 4 + 3];
            float pr = v.x * wr[q * 4] + v.y * wr[q * 4 + 1] + v.z * wr[q * 4 + 2] + v.w * wr[q * 4 + 3];
            pl += __shfl_xor(pl, 1); pl += __shfl_xor(pl, 2);
            pr += __shfl_xor(pr, 1); pr += __shfl_xor(pr, 2);
            if (q == 0) {
                el_out[g] = pl;
                if (d < N_DST2) er_out[(size_t)t * N_DST2 + d] = pr;
            }
        }
    } else {
        float4 v1, v2, v3;
        v1.x = __shfl_xor(v.x, 1); v1.y = __shfl_xor(v.y, 1); v1.z = __shfl_xor(v.z, 1); v1.w = __shfl_xor(v.w, 1);
        v2.x = __shfl_xor(v.x, 2); v2.y = __shfl_xor(v.y, 2); v2.z = __shfl_xor(v.z, 2); v2.w = __shfl_xor(v.w, 2);
        v3.x = __shfl_xor(v.x, 3); v3.y = __shfl_xor(v.y, 3); v3.z = __shfl_xor(v.z, 3); v3.w = __shfl_xor(v.w, 3);
        int obase = q * 8;
        float out8[8];
#pragma unroll
        for (int oo = 0; oo < 8; oo++) out8[oo] = 0.f;
#define ACCQ(Q, R0)                                                             \
        {                                                                       \
            int r0 = (R0) * 4;                                                  \
            _Pragma("unroll")                                                   \
            for (int oo = 0; oo < 8; oo++)                                      \
                out8[oo] += (Q).x * w2s[(r0 + 0) * C_OUT + obase + oo]          \
                          + (Q).y * w2s[(r0 + 1) * C_OUT + obase + oo]          \
                          + (Q).z * w2s[(r0 + 2) * C_OUT + obase + oo]          \
                          + (Q).w * w2s[(r0 + 3) * C_OUT + obase + oo];         \
        }
        ACCQ(v,  q);
        ACCQ(v1, q ^ 1);
        ACCQ(v2, q ^ 2);
        ACCQ(v3, q ^ 3);
#undef ACCQ
        if (eslot == 0) {
            float* op = outp + (size_t)g * C_OUT + obase;
            float4 w0 = make_float4(lrelu(out8[0], 0.01f), lrelu(out8[1], 0.01f),
                                    lrelu(out8[2], 0.01f), lrelu(out8[3], 0.01f));
            float4 w1 = make_float4(lrelu(out8[4], 0.01f), lrelu(out8[5], 0.01f),
                                    lrelu(out8[6], 0.01f), lrelu(out8[7], 0.01f));
            *reinterpret_cast<float4*>(op) = w0;
            *reinterpret_cast<float4*>(op + 4) = w1;
        }
    }
}

extern "C" void kernel_launch(void* const* d_in, const int* in_sizes, int n_in,
                              void* d_out, int out_size, void* d_ws, size_t ws_size,
                              hipStream_t stream)
{
    const float* node_feat = (const float*)d_in[0];
    const int*   esrc1     = (const int*)d_in[1];
    const int*   edst1     = (const int*)d_in[2];
    const float* ew1       = (const float*)d_in[3];
    const int*   esrc2     = (const int*)d_in[4];
    const int*   edst2     = (const int*)d_in[5];
    const float* ew2       = (const float*)d_in[6];
    const float* W1        = (const float*)d_in[7];
    const float* a_l1      = (const float*)d_in[8];
    const float* a_r1      = (const float*)d_in[9];
    const float* W2        = (const float*)d_in[10];
    const float* a_l2      = (const float*)d_in[11];
    const float* a_r2      = (const float*)d_in[12];
    float* out = (float*)d_out;

    float* ws = (float*)d_ws;
    float* hs1 = ws;                        // 9,600,000  [T][N_SRC][16]
    float* el1 = hs1 + 9600000;             //   600,000  [T][N_SRC]
    float* er1 = el1 + 600000;              //   240,000  [T][N_DST1]
    float* h1  = er1 + 240000;              // 3,840,000  [T][N_DST1][16]
    float* el2 = h1 + 3840000;              //   240,000  [T][N_DST1]
    float* er2 = el2 + 240000;              //   120,000  [T][N_DST2]
    float* wl2 = er2 + 120000;              //        16
    float* wr2 = wl2 + 16;                  //        16
    int2* sw1 = (int2*)(wr2 + 16);          // E1 (16B-aligned)
    int2* sw2 = sw1 + E1;                   // E2
    int* cnt1 = (int*)(sw2 + E2);           //  20,000 (16B-aligned)
    int* cnt2 = cnt1 + N_DST1;              //  10,000
    int* off1 = cnt2 + N_DST2;              //  20,001
    int* cur1 = off1 + N_DST1 + 1;          //  20,000
    int* off2 = cur1 + N_DST1;              //  10,001
    int* cur2 = off2 + N_DST2 + 1;          //  10,000

    k_zero<<<30, 256, 0, stream>>>((int4*)cnt1, (N_DST1 + N_DST2) / 4);
    k_hist<<<(E1 + E2 + 255) / 256, 256, 0, stream>>>(edst1, edst2, cnt1, cnt2);
    k_scan<<<3, 1024, 0, stream>>>(cnt1, off1, cur1, cnt2, off2, cur2,
                                   W2, a_l2, a_r2, wl2, wr2);
    k_scatter<<<(E1 + E2 + 255) / 256, 256, 0, stream>>>(
        esrc1, edst1, ew1, cur1, sw1,
        esrc2, edst2, ew2, cur2, sw2);

    {
        dim3 g((N_SRC + 63) / 64, T);
        k_transform1<<<g, 256, 0, stream>>>(node_feat, W1, a_l1, a_r1, hs1, el1, er1);
    }
    k_gat<N_DST1, N_SRC, false><<<(N_DST1 * T) / 16, 256, 0, stream>>>(
        off1, sw1, el1, er1, hs1, h1, wl2, wr2, el2, er2);
    k_gat<N_DST2, N_DST1, true><<<(N_DST2 * T) / 16, 256, 0, stream>>>(
        off2, sw2, el2, er2, h1, out, W2, nullptr, nullptr, nullptr);
}